// Round 1
// baseline (522.662 us; speedup 1.0000x reference)
//
#include <hip/hip_runtime.h>
#include <cmath>

// B=64, T=256 -> 16384 independent problems; NQ=32 queries (31 rows), NT=32 targets (cols)
#define NPROB 16384
#define PROBS_PER_BLOCK 8   // 256 threads, 32 lanes (half-wave) per problem

__device__ __forceinline__ float halfmin32(float x) {
  // min across each 32-lane half (xor masks < 32 never cross the half boundary)
  x = fminf(x, __shfl_xor(x, 1, 64));
  x = fminf(x, __shfl_xor(x, 2, 64));
  x = fminf(x, __shfl_xor(x, 4, 64));
  x = fminf(x, __shfl_xor(x, 8, 64));
  x = fminf(x, __shfl_xor(x, 16, 64));
  return x;
}

__global__ __launch_bounds__(256, 4) void matcher_kernel(
    const float* __restrict__ position,   // (BT, 32, 3)
    const float* __restrict__ velocity,   // (BT, 32, 3)
    const float* __restrict__ logits,     // (BT, 32, 5)
    const float* __restrict__ targets,    // (BT, 32, 18)
    float* __restrict__ out)              // C (BT,31,32) ++ pred_idx (BT,31) ++ tgt_idx (BT,31)
{
#pragma clang fp contract(off)
  __shared__ float sCm[PROBS_PER_BLOCK][992];    // masked cost, row-major 31x32
  __shared__ float sProb[PROBS_PER_BLOCK][160];  // 31 rows x 5 class probs
  __shared__ int   sValid[PROBS_PER_BLOCK][32];
  __shared__ int   sR2c[PROBS_PER_BLOCK][32];

  const int tid  = threadIdx.x;
  const int lane = tid & 63;
  const int rel  = lane & 31;      // column j = rel+1 ; row r = rel+1 for u storage
  const int hs   = lane & 32;      // 0 for lower half, 32 for upper half
  const int lp   = tid >> 5;       // local problem 0..7
  const int bt   = blockIdx.x * PROBS_PER_BLOCK + lp;

  const float* pos = position + (size_t)bt * 96;
  const float* vel = velocity + (size_t)bt * 96;
  const float* lg  = logits   + (size_t)bt * 160;
  const float* tg  = targets  + (size_t)bt * 576;

  // ---------- per-lane target fields (lane rel <-> target column rel) ----------
  const float* trow = tg + rel * 18;
  const float tp0 = trow[0],  tp1 = trow[1],  tp2 = trow[2];
  const float tv0 = trow[3],  tv1 = trow[4],  tv2 = trow[5];
  const float o0  = trow[14], o1  = trow[15], o2  = trow[16], o3 = trow[17];
  const float ssum = ((o0 + o1) + o2) + o3;
  const float mxo  = fmaxf(fmaxf(fmaxf(o0, o1), o2), o3);
  const int idx4 = (o0 == mxo) ? 0 : ((o1 == mxo) ? 1 : ((o2 == mxo) ? 2 : 3));
  const int cls5 = (ssum == 0.0f) ? 0 : (idx4 + 1);
  const int validc = (ssum > 0.0f && cls5 != 1) ? 1 : 0;
  sValid[lp][rel] = validc;

  // ---------- softmax of rows 1..31 (lane rel handles row rel+1) ----------
  if (rel < 31) {
    const float* lr = lg + (rel + 1) * 5;
    const float l0 = lr[0], l1 = lr[1], l2 = lr[2], l3 = lr[3], l4 = lr[4];
    const float m = fmaxf(fmaxf(fmaxf(fmaxf(l0, l1), l2), l3), l4);
    const float e0 = expf(l0 - m), e1 = expf(l1 - m), e2 = expf(l2 - m),
                e3 = expf(l3 - m), e4 = expf(l4 - m);
    const float sum = (((e0 + e1) + e2) + e3) + e4;
    sProb[lp][rel * 5 + 0] = e0 / sum;
    sProb[lp][rel * 5 + 1] = e1 / sum;
    sProb[lp][rel * 5 + 2] = e2 / sum;
    sProb[lp][rel * 5 + 3] = e3 / sum;
    sProb[lp][rel * 5 + 4] = e4 / sum;
  }
  __syncthreads();

  // ---------- cost matrix: C and masked Cm ----------
  float* outC = out + (size_t)bt * 992;
  for (int r = 0; r < 31; ++r) {
    const float pr0 = pos[(r + 1) * 3 + 0], pr1 = pos[(r + 1) * 3 + 1], pr2 = pos[(r + 1) * 3 + 2];
    const float vr0 = vel[(r + 1) * 3 + 0], vr1 = vel[(r + 1) * 3 + 1], vr2 = vel[(r + 1) * 3 + 2];
    const float cp = (fabsf(pr0 - tp0) + fabsf(pr1 - tp1)) + fabsf(pr2 - tp2);
    const float cv = (fabsf(vr0 - tv0) + fabsf(vr1 - tv1)) + fabsf(vr2 - tv2);
    const float ccl = -sProb[lp][r * 5 + cls5];
    const float Cv = (ccl + 5.0f * cp) + 2.0f * cv;   // W_CLASS=1, W_POS=5, W_VEL=2
    outC[r * 32 + rel] = Cv;
    sCm[lp][r * 32 + rel] = validc ? Cv : 1000000.0f; // BIG
  }
  // sCm column rel written & read by the same lane -> wave-order LDS, no barrier needed

  // ---------- Jonker-Volgenant LAP (rows 1..31, cols 1..32), half-wave parallel ----------
  const float INF = 1e18f;
  float u = 0.0f;   // u[rel+1] (rel<31 meaningful)
  float v = 0.0f;   // v[rel+1]
  int   p = 0;      // p[rel+1]: assigned row or 0
  const float* cmrow = &sCm[lp][0];

  for (int i = 1; i <= 31; ++i) {
    bool  used    = false;
    bool  rowUsed = (rel == i - 1);   // row i enters the tree (p[0]=i, used[0]=True)
    int   way     = 0;
    float minv;

    // --- peeled first Dijkstra iteration (j0 = 0, i0 = i) ---
    {
      const float u_i = __shfl(u, hs + (i - 1), 64);   // u[i] (== 0 here, read for faithfulness)
      const float a   = cmrow[(i - 1) * 32 + rel];
      minv = (a - u_i) - v;                            // all columns fresh (minv was INF)
    }
    float mval = halfmin32(minv);
    unsigned mh = (unsigned)(__ballot(minv == mval) >> hs);
    int   j0    = __ffs(mh);                           // first-index argmin == jnp.argmin
    float delta = mval;
    if (rowUsed) u += delta;                           // u[i] += delta
    minv -= delta;                                     // all cols unused
    int  pj     = __shfl(p, hs + j0 - 1, 64);
    bool active = (pj != 0);

    // --- main Dijkstra loop ---
    while (__ballot(active) != 0ull) {
      const int i0 = pj;
      if (active) {
        if (rel == j0 - 1) used = true;
        if (rel == i0 - 1) rowUsed = true;
      }
      const int   ri = active ? (i0 - 1) : 0;
      const float u0 = __shfl(u, hs + ri, 64);
      const float a2 = cmrow[ri * 32 + rel];
      const float c2 = (a2 - u0) - v;
      if (active && !used && c2 < minv) { minv = c2; way = j0; }
      const float cnd = used ? INF : minv;
      const float mv2 = halfmin32(cnd);
      const unsigned mh2 = (unsigned)(__ballot(cnd == mv2) >> hs);
      const int   j1 = __ffs(mh2);
      const float d2 = mv2;
      if (active) {
        if (rowUsed) u += d2;
        if (used) v -= d2; else minv -= d2;
        j0 = j1;
      }
      const int pjn = __shfl(p, hs + j0 - 1, 64);
      if (active) { pj = pjn; active = (pj != 0); }
    }

    // --- augmenting path: while j0 != 0: j1=way[j0]; p[j0]=p[j1]; j0=j1 ---
    bool aact = true;
    while (__ballot(aact) != 0ull) {
      const int jj  = aact ? j0 : 1;
      const int w1  = __shfl(way, hs + jj - 1, 64);
      const int src = (w1 == 0) ? 1 : w1;
      const int pv  = __shfl(p, hs + src - 1, 64);
      const int pja = (w1 == 0) ? i : pv;              // p[0] == current row i
      if (aact && rel == jj - 1) p = pja;
      if (aact) { j0 = w1; aact = (w1 != 0); }
    }
  }

  // ---------- outputs: row2col scatter, then pred_idx / tgt_idx ----------
  if (p > 0) sR2c[lp][p - 1] = rel;   // rows 1..31 each matched exactly once
  __syncthreads();
  if (rel < 31) {
    const int col = sR2c[lp][rel];
    const int av  = sValid[lp][col];
    const size_t base1 = (size_t)NPROB * 992;
    const size_t base2 = base1 + (size_t)NPROB * 31;
    out[base1 + (size_t)bt * 31 + rel] = av ? (float)(rel + 1) : -1.0f;
    out[base2 + (size_t)bt * 31 + rel] = av ? (float)col : -1.0f;
  }
}

extern "C" void kernel_launch(void* const* d_in, const int* in_sizes, int n_in,
                              void* d_out, int out_size, void* d_ws, size_t ws_size,
                              hipStream_t stream) {
  const float* position = (const float*)d_in[0];
  const float* velocity = (const float*)d_in[1];
  const float* logits   = (const float*)d_in[2];
  const float* targets  = (const float*)d_in[3];
  float* out = (float*)d_out;
  matcher_kernel<<<NPROB / PROBS_PER_BLOCK, 256, 0, stream>>>(
      position, velocity, logits, targets, out);
}

// Round 3
// 459.520 us; speedup vs baseline: 1.1374x; 1.1374x over previous
//
#include <hip/hip_runtime.h>
#include <cmath>

// B=64, T=256 -> 16384 independent problems; 31 rows x 32 cols LAP per problem.
#define NPROB 16384
#define PROBS_PER_BLOCK 8   // 256 threads, one half-wave (32 lanes) per problem

// DPP-based min step (v_mov_b32_dpp + v_min_f32, or fused v_min_f32_dpp).
template<int CTRL>
__device__ __forceinline__ float fmin_dpp(float x) {
  int s = __builtin_amdgcn_update_dpp(0, __float_as_int(x), CTRL, 0xF, 0xF, true);
  return fminf(x, __int_as_float(s));
}

// min across each 32-lane half. Under the ballot-predicated loop structure EXEC
// is always full-wave here, so every DPP/swizzle source lane is enabled.
__device__ __forceinline__ float halfmin32(float x) {
  x = fmin_dpp<0xB1>(x);    // quad_perm(1,0,3,2): xor1 -> pair min
  x = fmin_dpp<0x4E>(x);    // quad_perm(2,3,0,1): xor2 -> quad min
  x = fmin_dpp<0x141>(x);   // row_half_mirror (i^7 within 8) -> 8-min
  x = fmin_dpp<0x140>(x);   // row_mirror (i^15 within 16)    -> 16-min
  int s = __builtin_amdgcn_ds_swizzle(__float_as_int(x), 0x401F); // xor16 within 32
  return fminf(x, __int_as_float(s));
}

__global__ __launch_bounds__(256, 5) void matcher_kernel(
    const float* __restrict__ position,   // (BT, 32, 3)
    const float* __restrict__ velocity,   // (BT, 32, 3)
    const float* __restrict__ logits,     // (BT, 32, 5)
    const float* __restrict__ targets,    // (BT, 32, 18)
    float* __restrict__ out)              // C (BT,31,32) ++ pred_idx (BT,31) ++ tgt_idx (BT,31)
{
#pragma clang fp contract(off)
  // 992*4*8 = 31744 B cost + 32*4*8 = 1024 B r2c = exactly 32768 B -> 5 blocks/CU.
  // Separate typed arrays: no float/int punning -> no TBAA reordering hazard.
  __shared__ float sCm[PROBS_PER_BLOCK][992];
  __shared__ int   sR2c[PROBS_PER_BLOCK][32];

  const int tid  = threadIdx.x;
  const int lane = tid & 63;
  const int rel  = lane & 31;      // column j = rel+1 ; row r = rel+1 for u storage
  const int hs   = lane & 32;      // 0 lower half, 32 upper half
  const int lp   = tid >> 5;       // local problem 0..7
  const int bt   = blockIdx.x * PROBS_PER_BLOCK + lp;

  const float* pos = position + (size_t)bt * 96;
  const float* vel = velocity + (size_t)bt * 96;
  const float* lg  = logits   + (size_t)bt * 160;
  const float* tg  = targets  + (size_t)bt * 576;

  // ---------- per-lane target fields (lane rel <-> target column rel) ----------
  const float* trow = tg + rel * 18;
  const float tp0 = trow[0],  tp1 = trow[1],  tp2 = trow[2];
  const float tv0 = trow[3],  tv1 = trow[4],  tv2 = trow[5];
  const float o0  = trow[14], o1  = trow[15], o2  = trow[16], o3 = trow[17];
  const float ssum = ((o0 + o1) + o2) + o3;
  const float mxo  = fmaxf(fmaxf(fmaxf(o0, o1), o2), o3);
  const int idx4 = (o0 == mxo) ? 0 : ((o1 == mxo) ? 1 : ((o2 == mxo) ? 2 : 3));
  const int cls5 = (ssum == 0.0f) ? 0 : (idx4 + 1);
  const int validc = (ssum > 0.0f && cls5 != 1) ? 1 : 0;

  // ---------- per-lane softmax stats for row rel+1 (rel<31): max and sum ----------
  float m_l = 0.0f, s_l = 1.0f;
  if (rel < 31) {
    const float* lr = lg + (rel + 1) * 5;
    const float l0 = lr[0], l1 = lr[1], l2 = lr[2], l3 = lr[3], l4 = lr[4];
    m_l = fmaxf(fmaxf(fmaxf(fmaxf(l0, l1), l2), l3), l4);
    const float e0 = expf(l0 - m_l), e1 = expf(l1 - m_l), e2 = expf(l2 - m_l),
                e3 = expf(l3 - m_l), e4 = expf(l4 - m_l);
    s_l = (((e0 + e1) + e2) + e3) + e4;
  }

  // ---------- cost matrix: C (global) and masked Cm (LDS) ----------
  // (this stage validated in R2: output 0 passed)
  float* outC  = out + (size_t)bt * 992;
  float* cmrow = &sCm[lp][0];
  for (int r = 0; r < 31; ++r) {
    const float m_r = __shfl(m_l, hs + r, 64);
    const float s_r = __shfl(s_l, hs + r, 64);
    const float lgl = lg[(r + 1) * 5 + cls5];
    const float psel = expf(lgl - m_r) / s_r;          // bit-identical to softmax elem
    const float pr0 = pos[(r + 1) * 3 + 0], pr1 = pos[(r + 1) * 3 + 1], pr2 = pos[(r + 1) * 3 + 2];
    const float vr0 = vel[(r + 1) * 3 + 0], vr1 = vel[(r + 1) * 3 + 1], vr2 = vel[(r + 1) * 3 + 2];
    const float cp = (fabsf(pr0 - tp0) + fabsf(pr1 - tp1)) + fabsf(pr2 - tp2);
    const float cv = (fabsf(vr0 - tv0) + fabsf(vr1 - tv1)) + fabsf(vr2 - tv2);
    const float Cv = (-psel + 5.0f * cp) + 2.0f * cv;  // W_CLASS=1, W_POS=5, W_VEL=2
    outC[r * 32 + rel]  = Cv;
    cmrow[r * 32 + rel] = validc ? Cv : 1000000.0f;    // BIG
  }
  // cmrow column rel written & read by the same lane -> in-order LDS, no barrier

  // ---------- Jonker-Volgenant LAP: R1-verbatim solver (ballot-predicated) ----------
  const float INF = 1e18f;
  float u = 0.0f;   // u[rel+1]
  float v = 0.0f;   // v[rel+1]
  int   p = 0;      // p[rel+1]: matched row or 0

  for (int i = 1; i <= 31; ++i) {
    bool  used    = false;
    bool  rowUsed = (rel == i - 1);   // row i enters the tree
    int   way     = 0;
    float minv;

    // --- peeled first iteration (j0 = 0, i0 = i) ---
    {
      const float u_i = __shfl(u, hs + (i - 1), 64);
      const float a   = cmrow[(i - 1) * 32 + rel];
      minv = (a - u_i) - v;
    }
    float mval = halfmin32(minv);
    unsigned mh = (unsigned)(__ballot(minv == mval) >> hs);
    int   j0    = __ffs(mh);                 // first-index argmin == jnp.argmin
    float delta = mval;
    if (rowUsed) u += delta;
    minv -= delta;
    int  pj     = __shfl(p, hs + j0 - 1, 64);
    bool active = (pj != 0);

    // --- main Dijkstra loop (convergent: all 64 lanes execute, data-predicated) ---
    while (__ballot(active) != 0ull) {
      const int i0 = pj;
      if (active) {
        if (rel == j0 - 1) used = true;
        if (rel == i0 - 1) rowUsed = true;
      }
      const int   ri = active ? (i0 - 1) : 0;
      const float u0 = __shfl(u, hs + ri, 64);
      const float a2 = cmrow[ri * 32 + rel];
      const float c2 = (a2 - u0) - v;
      if (active && !used && c2 < minv) { minv = c2; way = j0; }
      const float cnd = used ? INF : minv;
      const float mv2 = halfmin32(cnd);
      const unsigned mh2 = (unsigned)(__ballot(cnd == mv2) >> hs);
      const int   j1 = __ffs(mh2);
      const float d2 = mv2;
      if (active) {
        if (rowUsed) u += d2;
        if (used) v -= d2; else minv -= d2;
        j0 = j1;
      }
      const int pjn = __shfl(p, hs + j0 - 1, 64);
      if (active) { pj = pjn; active = (pj != 0); }
    }

    // --- augmenting path ---
    bool aact = true;
    while (__ballot(aact) != 0ull) {
      const int jj  = aact ? j0 : 1;
      const int w1  = __shfl(way, hs + jj - 1, 64);
      const int src = (w1 == 0) ? 1 : w1;
      const int pv  = __shfl(p, hs + src - 1, 64);
      const int pja = (w1 == 0) ? i : pv;
      if (aact && rel == jj - 1) p = pja;
      if (aact) { j0 = w1; aact = (w1 != 0); }
    }
  }

  // ---------- outputs: invert p -> row2col, then pred_idx / tgt_idx ----------
  if (p > 0) sR2c[lp][p - 1] = rel;          // rows 0..30 all covered (perfect matching)
  const int col  = sR2c[lp][rel & 31];       // same-wave ordered (same-type accesses)
  const int colc = col & 31;
  const int av   = __shfl(validc, hs + colc, 64);  // full-wave shfl, then gated store
  if (rel < 31) {
    const size_t base1 = (size_t)NPROB * 992;
    const size_t base2 = base1 + (size_t)NPROB * 31;
    out[base1 + (size_t)bt * 31 + rel] = av ? (float)(rel + 1) : -1.0f;
    out[base2 + (size_t)bt * 31 + rel] = av ? (float)col : -1.0f;
  }
}

extern "C" void kernel_launch(void* const* d_in, const int* in_sizes, int n_in,
                              void* d_out, int out_size, void* d_ws, size_t ws_size,
                              hipStream_t stream) {
  const float* position = (const float*)d_in[0];
  const float* velocity = (const float*)d_in[1];
  const float* logits   = (const float*)d_in[2];
  const float* targets  = (const float*)d_in[3];
  float* out = (float*)d_out;
  matcher_kernel<<<NPROB / PROBS_PER_BLOCK, 256, 0, stream>>>(
      position, velocity, logits, targets, out);
}

// Round 5
// 434.056 us; speedup vs baseline: 1.2041x; 1.0587x over previous
//
#include <hip/hip_runtime.h>
#include <cmath>

// B=64, T=256 -> 16384 independent problems; 31 rows x 32 cols LAP per problem.
// Solver must replicate the reference's fp32 arithmetic BIT-EXACTLY (incl. the
// BIG=1e6 potential trajectories and their 0.0625 quantization of reduced costs,
// which determine tie-breaks). R3-verbatim per-lane arithmetic; divergent loops.
#define NPROB 16384
#define PROBS_PER_BLOCK 4   // 128 threads, one half-wave (32 lanes) per problem

template<int CTRL>
__device__ __forceinline__ float fmin_dpp(float x) {
  int s = __builtin_amdgcn_update_dpp(0, __float_as_int(x), CTRL, 0xF, 0xF, true);
  return fminf(x, __int_as_float(s));
}

// min across each 32-lane half. All DPP/swizzle sources stay inside the 32-lane
// half, so exec-masked divergence between halves never sources a disabled lane.
__device__ __forceinline__ float halfmin32(float x) {
  x = fmin_dpp<0xB1>(x);    // quad_perm xor1
  x = fmin_dpp<0x4E>(x);    // quad_perm xor2
  x = fmin_dpp<0x141>(x);   // row_half_mirror -> 8-min
  x = fmin_dpp<0x140>(x);   // row_mirror      -> 16-min
  int s = __builtin_amdgcn_ds_swizzle(__float_as_int(x), 0x401F); // xor16
  return fminf(x, __int_as_float(s));
}

__global__ __launch_bounds__(128, 5) void matcher_kernel(
    const float* __restrict__ position,   // (BT, 32, 3)
    const float* __restrict__ velocity,   // (BT, 32, 3)
    const float* __restrict__ logits,     // (BT, 32, 5)
    const float* __restrict__ targets,    // (BT, 32, 18)
    float* __restrict__ out)              // C (BT,31,32) ++ pred_idx (BT,31) ++ tgt_idx (BT,31)
{
#pragma clang fp contract(off)
  // 4*992*4 = 15872 B cost + 4*32*4 = 512 B r2c = 16384 B -> 10 blocks/CU, 20 waves/CU.
  __shared__ float sCm[PROBS_PER_BLOCK][992];
  __shared__ int   sR2c[PROBS_PER_BLOCK][32];

  const int tid  = threadIdx.x;
  const int lane = tid & 63;
  const int rel  = lane & 31;      // column j = rel+1 ; row r = rel+1 for u storage
  const int hs   = lane & 32;      // 0 lower half, 32 upper half
  const int lp   = tid >> 5;       // local problem 0..3
  const int bt   = blockIdx.x * PROBS_PER_BLOCK + lp;

  const float* pos = position + (size_t)bt * 96;
  const float* vel = velocity + (size_t)bt * 96;
  const float* lg  = logits   + (size_t)bt * 160;
  const float* tg  = targets  + (size_t)bt * 576;

  // ---------- per-lane target fields (lane rel <-> target column rel) ----------
  const float* trow = tg + rel * 18;
  const float tp0 = trow[0],  tp1 = trow[1],  tp2 = trow[2];
  const float tv0 = trow[3],  tv1 = trow[4],  tv2 = trow[5];
  const float o0  = trow[14], o1  = trow[15], o2  = trow[16], o3 = trow[17];
  const float ssum = ((o0 + o1) + o2) + o3;
  const float mxo  = fmaxf(fmaxf(fmaxf(o0, o1), o2), o3);
  const int idx4 = (o0 == mxo) ? 0 : ((o1 == mxo) ? 1 : ((o2 == mxo) ? 2 : 3));
  const int cls5 = (ssum == 0.0f) ? 0 : (idx4 + 1);
  const int validc = (ssum > 0.0f && cls5 != 1) ? 1 : 0;

  // ---------- per-lane softmax stats for row rel+1 (rel<31) ----------
  float m_l = 0.0f, s_l = 1.0f;
  if (rel < 31) {
    const float* lr = lg + (rel + 1) * 5;
    const float l0 = lr[0], l1 = lr[1], l2 = lr[2], l3 = lr[3], l4 = lr[4];
    m_l = fmaxf(fmaxf(fmaxf(fmaxf(l0, l1), l2), l3), l4);
    const float e0 = expf(l0 - m_l), e1 = expf(l1 - m_l), e2 = expf(l2 - m_l),
                e3 = expf(l3 - m_l), e4 = expf(l4 - m_l);
    s_l = (((e0 + e1) + e2) + e3) + e4;
  }

  // ---------- cost matrix: C (global) and masked Cm (LDS) ----------
  float* outC  = out + (size_t)bt * 992;
  float* cmrow = &sCm[lp][0];
  for (int r = 0; r < 31; ++r) {
    const float m_r = __shfl(m_l, hs + r, 64);
    const float s_r = __shfl(s_l, hs + r, 64);
    const float lgl = lg[(r + 1) * 5 + cls5];
    const float psel = expf(lgl - m_r) / s_r;          // bit-identical softmax elem
    const float pr0 = pos[(r + 1) * 3 + 0], pr1 = pos[(r + 1) * 3 + 1], pr2 = pos[(r + 1) * 3 + 2];
    const float vr0 = vel[(r + 1) * 3 + 0], vr1 = vel[(r + 1) * 3 + 1], vr2 = vel[(r + 1) * 3 + 2];
    const float cp = (fabsf(pr0 - tp0) + fabsf(pr1 - tp1)) + fabsf(pr2 - tp2);
    const float cv = (fabsf(vr0 - tv0) + fabsf(vr1 - tv1)) + fabsf(vr2 - tv2);
    const float Cv = (-psel + 5.0f * cp) + 2.0f * cv;  // W_CLASS=1, W_POS=5, W_VEL=2
    outC[r * 32 + rel]  = Cv;
    cmrow[r * 32 + rel] = validc ? Cv : 1000000.0f;    // BIG
  }
  // cmrow column rel written & read by the same half-wave -> in-order LDS, no barrier

  // ---------- Jonker-Volgenant LAP: R3 arithmetic, divergent control flow ----------
  const float INF = 1e18f;
  float u = 0.0f;   // u[rel+1]
  float v = 0.0f;   // v[rel+1]
  int   p = 0;      // p[rel+1]: matched row or 0

  for (int i = 1; i <= 31; ++i) {
    bool  used    = false;
    bool  rowUsed = (rel == i - 1);   // row i enters the tree
    int   way     = 0;

    // --- peeled first iteration (j0 = 0, i0 = i); fully convergent ---
    float minv;
    {
      const float u_i = __shfl(u, hs + (i - 1), 64);
      const float a   = cmrow[(i - 1) * 32 + rel];
      minv = (a - u_i) - v;
    }
    const float mval = halfmin32(minv);
    const unsigned mh = (unsigned)(__ballot(minv == mval) >> hs);
    int j0 = __ffs(mh);                       // first-index argmin == jnp.argmin
    if (rowUsed) u += mval;
    minv -= mval;
    int pj = __shfl(p, hs + j0 - 1, 64);

    // --- main Dijkstra loop: per-half-uniform condition, exec-mask divergence ---
    while (pj != 0) {
      const int i0 = pj;
      used    = used    | (rel == (j0 - 1));
      rowUsed = rowUsed | (rel == (i0 - 1));
      const float u0 = __shfl(u, hs + (i0 - 1), 64);
      const float a2 = cmrow[(i0 - 1) * 32 + rel];
      const float c2 = (a2 - u0) - v;
      if (!used && c2 < minv) { minv = c2; way = j0; }
      const float cnd = used ? INF : minv;
      const float mv2 = halfmin32(cnd);
      const unsigned mh2 = (unsigned)(__ballot(cnd == mv2) >> hs);
      j0 = __ffs(mh2);
      const float d2 = mv2;
      if (rowUsed) u += d2;
      if (used) v -= d2; else minv -= d2;
      pj = __shfl(p, hs + j0 - 1, 64);
    }

    // --- augmenting path (divergent) ---
    while (j0 != 0) {
      const int w1  = __shfl(way, hs + j0 - 1, 64);
      const int src = (w1 == 0) ? 1 : w1;
      const int pv  = __shfl(p, hs + src - 1, 64);
      const int pja = (w1 == 0) ? i : pv;
      if (rel == j0 - 1) p = pja;
      j0 = w1;
    }
  }

  // ---------- outputs: invert p -> row2col, then pred_idx / tgt_idx ----------
  if (p > 0) sR2c[lp][p - 1] = rel;          // rows 0..30 all covered
  const int col  = sR2c[lp][rel & 31];
  const int colc = col & 31;
  const int av   = __shfl(validc, hs + colc, 64);
  if (rel < 31) {
    const size_t base1 = (size_t)NPROB * 992;
    const size_t base2 = base1 + (size_t)NPROB * 31;
    out[base1 + (size_t)bt * 31 + rel] = av ? (float)(rel + 1) : -1.0f;
    out[base2 + (size_t)bt * 31 + rel] = av ? (float)col : -1.0f;
  }
}

extern "C" void kernel_launch(void* const* d_in, const int* in_sizes, int n_in,
                              void* d_out, int out_size, void* d_ws, size_t ws_size,
                              hipStream_t stream) {
  const float* position = (const float*)d_in[0];
  const float* velocity = (const float*)d_in[1];
  const float* logits   = (const float*)d_in[2];
  const float* targets  = (const float*)d_in[3];
  float* out = (float*)d_out;
  matcher_kernel<<<NPROB / PROBS_PER_BLOCK, 128, 0, stream>>>(
      position, velocity, logits, targets, out);
}

// Round 6
// 381.909 us; speedup vs baseline: 1.3686x; 1.1365x over previous
//
#include <hip/hip_runtime.h>
#include <cmath>

// B=64, T=256 -> 16384 independent problems; 31 rows x 32 cols LAP per problem.
// Solver replicates the reference's fp32 arithmetic BIT-EXACTLY (incl. BIG=1e6
// potential trajectories whose 0.0625-quantized reduced costs decide tie-breaks).
#define NPROB 16384
#define PROBS_PER_BLOCK 4   // 128 threads, one half-wave (32 lanes) per problem

template<int CTRL>
__device__ __forceinline__ float fmin_dpp(float x) {
  int s = __builtin_amdgcn_update_dpp(0, __float_as_int(x), CTRL, 0xF, 0xF, true);
  return fminf(x, __int_as_float(s));
}

// min across each 32-lane half; all sources stay inside the 32-lane half.
__device__ __forceinline__ float halfmin32(float x) {
  x = fmin_dpp<0xB1>(x);    // quad_perm xor1
  x = fmin_dpp<0x4E>(x);    // quad_perm xor2
  x = fmin_dpp<0x141>(x);   // row_half_mirror -> 8-min
  x = fmin_dpp<0x140>(x);   // row_mirror      -> 16-min
  int s = __builtin_amdgcn_ds_swizzle(__float_as_int(x), 0x401F); // xor16
  return fminf(x, __int_as_float(s));
}

__device__ __forceinline__ int bperm_i(int addr, int v) {
  return __builtin_amdgcn_ds_bpermute(addr, v);
}
__device__ __forceinline__ float bperm_f(int addr, float v) {
  return __int_as_float(__builtin_amdgcn_ds_bpermute(addr, __float_as_int(v)));
}

__global__ __launch_bounds__(128, 5) void matcher_kernel(
    const float* __restrict__ position,   // (BT, 32, 3)
    const float* __restrict__ velocity,   // (BT, 32, 3)
    const float* __restrict__ logits,     // (BT, 32, 5)
    const float* __restrict__ targets,    // (BT, 32, 18)
    float* __restrict__ out)              // C (BT,31,32) ++ pred_idx (BT,31) ++ tgt_idx (BT,31)
{
#pragma clang fp contract(off)
  // 4*992*4 + 4*32*4 = 16384 B -> 10 blocks/CU, 20 waves/CU.
  __shared__ float sCm[PROBS_PER_BLOCK][992];
  __shared__ int   sR2c[PROBS_PER_BLOCK][32];

  const int tid  = threadIdx.x;
  const int lane = tid & 63;
  const int rel  = lane & 31;      // column j-1 (0-based col); also row r=rel+1 for u storage
  const int hs   = lane & 32;      // 0 lower half, 32 upper half
  const int hs4  = hs * 4;
  const int relp1 = rel + 1;
  const int lp   = tid >> 5;       // local problem 0..3
  const int bt   = blockIdx.x * PROBS_PER_BLOCK + lp;

  const float* pos = position + (size_t)bt * 96;
  const float* vel = velocity + (size_t)bt * 96;
  const float* lg  = logits   + (size_t)bt * 160;
  const float* tg  = targets  + (size_t)bt * 576;

  // ---------- per-lane target fields (lane rel <-> target column rel) ----------
  const float* trow = tg + rel * 18;
  const float tp0 = trow[0],  tp1 = trow[1],  tp2 = trow[2];
  const float tv0 = trow[3],  tv1 = trow[4],  tv2 = trow[5];
  const float o0  = trow[14], o1  = trow[15], o2  = trow[16], o3 = trow[17];
  const float ssum = ((o0 + o1) + o2) + o3;
  const float mxo  = fmaxf(fmaxf(fmaxf(o0, o1), o2), o3);
  const int idx4 = (o0 == mxo) ? 0 : ((o1 == mxo) ? 1 : ((o2 == mxo) ? 2 : 3));
  const int cls5 = (ssum == 0.0f) ? 0 : (idx4 + 1);
  const int validc = (ssum > 0.0f && cls5 != 1) ? 1 : 0;

  // ---------- per-lane softmax stats for row rel+1 (rel<31) ----------
  float m_l = 0.0f, s_l = 1.0f;
  if (rel < 31) {
    const float* lr = lg + (rel + 1) * 5;
    const float l0 = lr[0], l1 = lr[1], l2 = lr[2], l3 = lr[3], l4 = lr[4];
    m_l = fmaxf(fmaxf(fmaxf(fmaxf(l0, l1), l2), l3), l4);
    const float e0 = expf(l0 - m_l), e1 = expf(l1 - m_l), e2 = expf(l2 - m_l),
                e3 = expf(l3 - m_l), e4 = expf(l4 - m_l);
    s_l = (((e0 + e1) + e2) + e3) + e4;
  }

  // ---------- cost matrix: C (global) and masked Cm (LDS) ----------
  float* outC  = out + (size_t)bt * 992;
  float* cmrow = &sCm[lp][0];
  for (int r = 0; r < 31; ++r) {
    const float m_r = __shfl(m_l, hs + r, 64);
    const float s_r = __shfl(s_l, hs + r, 64);
    const float lgl = lg[(r + 1) * 5 + cls5];
    const float psel = expf(lgl - m_r) / s_r;          // bit-identical softmax elem
    const float pr0 = pos[(r + 1) * 3 + 0], pr1 = pos[(r + 1) * 3 + 1], pr2 = pos[(r + 1) * 3 + 2];
    const float vr0 = vel[(r + 1) * 3 + 0], vr1 = vel[(r + 1) * 3 + 1], vr2 = vel[(r + 1) * 3 + 2];
    const float cp = (fabsf(pr0 - tp0) + fabsf(pr1 - tp1)) + fabsf(pr2 - tp2);
    const float cv = (fabsf(vr0 - tv0) + fabsf(vr1 - tv1)) + fabsf(vr2 - tv2);
    const float Cv = (-psel + 5.0f * cp) + 2.0f * cv;  // W_CLASS=1, W_POS=5, W_VEL=2
    outC[r * 32 + rel]  = Cv;
    cmrow[r * 32 + rel] = validc ? Cv : 1000000.0f;    // BIG
  }
  // cmrow written & read by the same half-wave -> in-order LDS, no barrier

  // ---------- Jonker-Volgenant LAP: bit-exact, trimmed pop loop ----------
  const float INF = 1e18f;
  float u = 0.0f;   // u[rel+1]
  float v = 0.0f;   // v[rel+1]
  int   p = 0;      // p[rel+1]: matched row (1-based) or 0

  for (int i = 1; i <= 31; ++i) {
    // uq[j] = u[p[j]] snapshot; maintained bit-exactly via the same add sequence
    // the reference applies to u[p[j]] (reads only hit not-yet-used cols).
    float uq = bperm_f(hs4 + 4 * p - 4, u);   // p==0 -> garbage lane, never read
    const float u_i = __shfl(u, hs + (i - 1), 64);

    bool  used = false;
    float rowf = (rel == i - 1) ? 1.0f : 0.0f;  // 1.0 for rows in the tree
    int   way  = -1;                             // 0-based pred col, -1 = root

    // --- peeled first iteration (tree = {row i}, all cols fresh) ---
    float minv = (cmrow[(i - 1) * 32 + rel] - u_i) - v;
    const float mval = halfmin32(minv);
    unsigned mh = (unsigned)(__ballot(minv == mval) >> hs);
    int j0 = (int)__builtin_ctz(mh);            // 0-based; first-index argmin
    u = fmaf(rowf, mval, u);                    // u[i] += delta (others +0, exact)
    minv -= mval;
    int   pj = bperm_i(hs4 + 4 * j0, p);
    float u0 = bperm_f(hs4 + 4 * j0, uq);       // u[p[j0]] (valid when pj!=0)

    // --- main Dijkstra loop (per-half divergent) ---
    while (pj != 0) {
      used = used | (rel == j0);                // mark popped col
      rowf = (relp1 == pj) ? 1.0f : rowf;       // its row enters the tree
      const float a2 = cmrow[pj * 32 - 32 + rel];
      const float c2 = (a2 - u0) - v;
      if (!used && c2 < minv) { minv = c2; way = j0; }
      const float cnd = used ? INF : minv;
      const float mv2 = halfmin32(cnd);
      mh = (unsigned)(__ballot(cnd == mv2) >> hs);
      j0 = (int)__builtin_ctz(mh);
      const float d2 = mv2;
      const float dv = used ? d2 : 0.0f;
      u = fmaf(rowf, d2, u);                    // tree rows += delta
      v -= dv;                                  // used cols  -= delta
      uq += dv;                                 // tracks u[p[j]] for used cols
      minv -= d2;                               // used lanes' minv is dead
      pj = bperm_i(hs4 + 4 * j0, p);            // independent, same-address
      u0 = bperm_f(hs4 + 4 * j0, uq);           //   broadcasts
    }

    // --- augmenting path (j0 = free col, 0-based) ---
    while (true) {
      const int w1 = __shfl(way, hs + j0, 64);               // pred col or -1
      const int pv = __shfl(p, hs + ((w1 < 0) ? 0 : w1), 64);
      const int pja = (w1 < 0) ? i : pv;
      if (rel == j0) p = pja;
      if (w1 < 0) break;
      j0 = w1;
    }
  }

  // ---------- outputs: invert p -> row2col, then pred_idx / tgt_idx ----------
  if (p > 0) sR2c[lp][p - 1] = rel;          // rows 0..30 all covered
  const int col  = sR2c[lp][rel & 31];
  const int colc = col & 31;
  const int av   = __shfl(validc, hs + colc, 64);
  if (rel < 31) {
    const size_t base1 = (size_t)NPROB * 992;
    const size_t base2 = base1 + (size_t)NPROB * 31;
    out[base1 + (size_t)bt * 31 + rel] = av ? (float)(rel + 1) : -1.0f;
    out[base2 + (size_t)bt * 31 + rel] = av ? (float)col : -1.0f;
  }
}

extern "C" void kernel_launch(void* const* d_in, const int* in_sizes, int n_in,
                              void* d_out, int out_size, void* d_ws, size_t ws_size,
                              hipStream_t stream) {
  const float* position = (const float*)d_in[0];
  const float* velocity = (const float*)d_in[1];
  const float* logits   = (const float*)d_in[2];
  const float* targets  = (const float*)d_in[3];
  float* out = (float*)d_out;
  matcher_kernel<<<NPROB / PROBS_PER_BLOCK, 128, 0, stream>>>(
      position, velocity, logits, targets, out);
}